// Round 2
// baseline (223.801 us; speedup 1.0000x reference)
//
#include <hip/hip_runtime.h>
#include <math.h>

#define H 128
#define HID 512

struct Ws {
    unsigned long long best;   // packed (fkey(score)<<32) | (0xFFFFFFFF - idx)
    float Z;
    float s_b;
    unsigned int done;
    float u[H];
};

__device__ __forceinline__ unsigned int fkey(float f) {
    unsigned int u = __float_as_uint(f);
    return (u & 0x80000000u) ? ~u : (u | 0x80000000u);
}
__device__ __forceinline__ float inv_fkey(unsigned int k) {
    return __uint_as_float((k & 0x80000000u) ? (k ^ 0x80000000u) : ~k);
}

// ---------------- prep: ONE block, 1024 threads, no global atomics ------------
// phi1 = W1*v_i + b1 ; u = W2^T phi1 ; s_b = phi1.b2 ; zero-init Z/best/done
__global__ __launch_bounds__(1024)
void prep_kernel(const float* __restrict__ outp, const float* __restrict__ W1,
                 const float* __restrict__ b1, const float* __restrict__ W2,
                 const float* __restrict__ b2, const int* __restrict__ prev,
                 Ws* __restrict__ ws) {
    __shared__ float phi1_s[HID];
    __shared__ float sb_s[32];
    __shared__ float u_part[8][H];
    int t = threadIdx.x;
    int lane = t & 63;
    int c = lane & 31;
    int g = t >> 5;            // half-wave id 0..31, each owns 16 rows of phi1
    const float4* vi = (const float4*)(outp + (size_t)prev[0] * H);
    float4 v = vi[c];
    float sb = 0.f;
#pragma unroll 4
    for (int r = 0; r < 16; ++r) {
        int k = g * 16 + r;
        float4 w = ((const float4*)(W1 + (size_t)k * H))[c];
        float d = w.x * v.x + w.y * v.y + w.z * v.z + w.w * v.w;
        d += __shfl_xor(d, 16);
        d += __shfl_xor(d, 8);
        d += __shfl_xor(d, 4);
        d += __shfl_xor(d, 2);
        d += __shfl_xor(d, 1);
        if (c == 0) {
            float phi = d + b1[k];
            phi1_s[k] = phi;
            sb += phi * b2[k];
        }
    }
    if (c == 0) sb_s[g] = sb;
    __syncthreads();
    // u[h] = sum_k phi1[k] * W2[k][h]; thread: h = t&127, k-range by g2 = t>>7
    int h = t & 127;
    int g2 = t >> 7;           // 0..7
    float up = 0.f;
#pragma unroll 8
    for (int kk = 0; kk < 64; ++kk) {
        int k = g2 * 64 + kk;
        up += phi1_s[k] * W2[(size_t)k * H + h];
    }
    u_part[g2][h] = up;
    __syncthreads();
    if (t < H) {
        float s = 0.f;
#pragma unroll
        for (int i = 0; i < 8; ++i) s += u_part[i][h];
        ws->u[h] = s;
    }
    if (t == 0) {
        float s = 0.f;
#pragma unroll
        for (int i = 0; i < 32; ++i) s += sb_s[i];
        ws->s_b = s;
        ws->Z = 0.f;
        ws->best = 0ull;
        ws->done = 0u;
    }
}

// ---------------- main streaming pass + fused finalize ------------------------
// Tile = 64 rows per block-iteration. Wave w: rows base+w*16 .. +15.
// Half-wave (32 lanes) handles 8 rows: row = base + w*16 + hv + 2*r.
// 8 float4 loads issued back-to-back (16 in flight per wave), 8 independent
// butterfly reduce chains, tail fanned over lanes 0..7.
__global__ __launch_bounds__(256)
void score_kernel(const float4* __restrict__ xv, const float* __restrict__ adj,
                  Ws* __restrict__ ws, int n, int ntiles, int grid,
                  float* __restrict__ outp) {
    __shared__ float zs[4];
    __shared__ unsigned long long bs[4];
    const float inv = 0.04419417382415922f;   // 1/sqrt(512)
    int t = threadIdx.x;
    int lane = t & 63;
    int c = lane & 31;
    int hv = lane >> 5;
    int w = t >> 6;
    float s_b = ws->s_b;
    float4 uv = ((const float4*)ws->u)[c];
    float zloc = 0.f;
    float bscore = -3.4e38f;
    int bidx = -1;
    for (int tile = blockIdx.x; tile < ntiles; tile += grid) {
        int base = tile * 64 + w * 16 + hv;
        float4 x[8];
#pragma unroll
        for (int r = 0; r < 8; ++r) {
            int row = base + 2 * r;
            if (row >= n) row = n - 1;            // clamp (value unused OOB)
            x[r] = xv[(size_t)row * 32 + c];
        }
        float d[8];
#pragma unroll
        for (int r = 0; r < 8; ++r) {
            float dd = x[r].x * uv.x + x[r].y * uv.y + x[r].z * uv.z + x[r].w * uv.w;
            dd += __shfl_xor(dd, 16);
            dd += __shfl_xor(dd, 8);
            dd += __shfl_xor(dd, 4);
            dd += __shfl_xor(dd, 2);
            dd += __shfl_xor(dd, 1);
            d[r] = dd;                            // full sum in ALL 32 lanes
        }
        // lanes 0..7 each own one row's tail
        if (c < 8) {
            int row = base + 2 * c;
            if (row < n) {
                float dm = d[0];
#pragma unroll
                for (int r = 1; r < 8; ++r) dm = (c == r) ? d[r] : dm;
                float a = adj[row];
                float attn = 0.f;
                if (a != 0.f) {
                    float score = (s_b + a * dm) * inv;
                    float e = __expf(2.f * score);        // fast tanh
                    attn = 10.f * ((e - 1.f) / (e + 1.f));
                    if (score > bscore) { bscore = score; bidx = row; }
                }
                zloc += __expf(attn);
            }
        }
    }
    // wave-wide reduce (64 lanes)
#pragma unroll
    for (int m = 32; m >= 1; m >>= 1) zloc += __shfl_xor(zloc, m);
    unsigned long long pk = 0ull;
    if (bidx >= 0)
        pk = ((unsigned long long)fkey(bscore) << 32) |
             (unsigned long long)(0xFFFFFFFFu - (unsigned int)bidx);
#pragma unroll
    for (int m = 32; m >= 1; m >>= 1) {
        unsigned long long o = __shfl_xor(pk, m);
        if (o > pk) pk = o;
    }
    if (lane == 0) { zs[w] = zloc; bs[w] = pk; }
    __syncthreads();
    if (t == 0) {
        float z = zs[0] + zs[1] + zs[2] + zs[3];
        unsigned long long p2 = bs[0];
#pragma unroll
        for (int i = 1; i < 4; ++i) if (bs[i] > p2) p2 = bs[i];
        atomicAdd(&ws->Z, z);
        atomicMax(&ws->best, p2);
        __threadfence();
        if (atomicAdd(&ws->done, 1u) == (unsigned)(grid - 1)) {
            // last block: finalize
            unsigned long long b = atomicMax(&ws->best, 0ull);   // coherent read
            float Z = atomicAdd(&ws->Z, 0.f);
            unsigned int idx = 0xFFFFFFFFu - (unsigned int)(b & 0xFFFFFFFFu);
            float score = inv_fkey((unsigned int)(b >> 32));
            float p = __expf(10.f * tanhf(score)) / Z;
            if (b == 0ull) { idx = 0; p = 0.f; }
            outp[0] = (float)idx;
            outp[1] = p;
        }
    }
}

extern "C" void kernel_launch(void* const* d_in, const int* in_sizes, int n_in,
                              void* d_out, int out_size, void* d_ws, size_t ws_size,
                              hipStream_t stream) {
    const float* outp = (const float*)d_in[0];
    const float* adj  = (const float*)d_in[1];
    const float* W1   = (const float*)d_in[2];
    const float* b1   = (const float*)d_in[3];
    const float* W2   = (const float*)d_in[4];
    const float* b2   = (const float*)d_in[5];
    const int*   prev = (const int*)d_in[6];
    int n = in_sizes[1];                       // N = 200000
    Ws* ws = (Ws*)d_ws;

    int ntiles = (n + 63) / 64;                // 3125
    int grid = 1042;                           // ~3 tiles/block, ~4 blocks/CU

    prep_kernel<<<1, 1024, 0, stream>>>(outp, W1, b1, W2, b2, prev, ws);
    score_kernel<<<grid, 256, 0, stream>>>((const float4*)outp, adj, ws, n,
                                           ntiles, grid, (float*)d_out);
}

// Round 3
// 185.147 us; speedup vs baseline: 1.2088x; 1.2088x over previous
//
#include <hip/hip_runtime.h>
#include <math.h>

#define H 128
#define HID 512
#define GRID 2048          // score blocks == partial slots

struct Ws {
    float s_b;
    float pad;
    float u[H];                          // offset 8..519
    unsigned long long best_part[GRID];  // 8-aligned
    float Z_part[GRID];
};

__device__ __forceinline__ unsigned int fkey(float f) {
    unsigned int u = __float_as_uint(f);
    return (u & 0x80000000u) ? ~u : (u | 0x80000000u);
}
__device__ __forceinline__ float inv_fkey(unsigned int k) {
    return __uint_as_float((k & 0x80000000u) ? (k ^ 0x80000000u) : ~k);
}

// ---------------- prep: ONE block, 1024 threads, no global atomics ------------
__global__ __launch_bounds__(1024)
void prep_kernel(const float* __restrict__ outp, const float* __restrict__ W1,
                 const float* __restrict__ b1, const float* __restrict__ W2,
                 const float* __restrict__ b2, const int* __restrict__ prev,
                 Ws* __restrict__ ws) {
    __shared__ float phi1_s[HID];
    __shared__ float sb_s[32];
    __shared__ float u_part[8][H];
    int t = threadIdx.x;
    int lane = t & 63;
    int c = lane & 31;
    int g = t >> 5;            // half-wave id 0..31, each owns 16 rows of phi1
    const float4* vi = (const float4*)(outp + (size_t)prev[0] * H);
    float4 v = vi[c];
    float sb = 0.f;
#pragma unroll 4
    for (int r = 0; r < 16; ++r) {
        int k = g * 16 + r;
        float4 w = ((const float4*)(W1 + (size_t)k * H))[c];
        float d = w.x * v.x + w.y * v.y + w.z * v.z + w.w * v.w;
        d += __shfl_xor(d, 16);
        d += __shfl_xor(d, 8);
        d += __shfl_xor(d, 4);
        d += __shfl_xor(d, 2);
        d += __shfl_xor(d, 1);
        if (c == 0) {
            float phi = d + b1[k];
            phi1_s[k] = phi;
            sb += phi * b2[k];
        }
    }
    if (c == 0) sb_s[g] = sb;
    __syncthreads();
    int h = t & 127;
    int g2 = t >> 7;           // 0..7
    float up = 0.f;
#pragma unroll 8
    for (int kk = 0; kk < 64; ++kk) {
        int k = g2 * 64 + kk;
        up += phi1_s[k] * W2[(size_t)k * H + h];
    }
    u_part[g2][h] = up;
    __syncthreads();
    if (t < H) {
        float s = 0.f;
#pragma unroll
        for (int i = 0; i < 8; ++i) s += u_part[i][h];
        ws->u[h] = s;
    }
    if (t == 0) {
        float s = 0.f;
#pragma unroll
        for (int i = 0; i < 32; ++i) s += sb_s[i];
        ws->s_b = s;
    }
}

// ---------------- main streaming pass: NO global atomics ----------------------
// Tile = 32 rows/block-iter. Wave w owns rows tile*32 + w*8 .. +7.
// Half-wave handles 4 rows (row = base + 2r), 4 float4 loads in flight,
// independent butterfly chains, tail fanned over lanes 0..3.
__global__ __launch_bounds__(256)
void score_kernel(const float4* __restrict__ xv, const float* __restrict__ adj,
                  Ws* __restrict__ ws, int n, int ntiles) {
    __shared__ float zs[4];
    __shared__ unsigned long long bs[4];
    const float inv = 0.04419417382415922f;   // 1/sqrt(512)
    int t = threadIdx.x;
    int lane = t & 63;
    int c = lane & 31;
    int hv = lane >> 5;
    int w = t >> 6;
    float s_b = ws->s_b;
    float4 uv = ((const float4*)ws->u)[c];
    float zloc = 0.f;
    float bscore = -3.4e38f;
    int bidx = -1;
    for (int tile = blockIdx.x; tile < ntiles; tile += GRID) {
        int base = tile * 32 + w * 8 + hv;
        float4 x[4];
#pragma unroll
        for (int r = 0; r < 4; ++r) {
            int row = base + 2 * r;
            if (row >= n) row = n - 1;            // clamp (value unused OOB)
            x[r] = xv[(size_t)row * 32 + c];
        }
        float d[4];
#pragma unroll
        for (int r = 0; r < 4; ++r) {
            float dd = x[r].x * uv.x + x[r].y * uv.y + x[r].z * uv.z + x[r].w * uv.w;
            dd += __shfl_xor(dd, 16);
            dd += __shfl_xor(dd, 8);
            dd += __shfl_xor(dd, 4);
            dd += __shfl_xor(dd, 2);
            dd += __shfl_xor(dd, 1);
            d[r] = dd;
        }
        if (c < 4) {
            int row = base + 2 * c;
            if (row < n) {
                float dm = d[0];
#pragma unroll
                for (int r = 1; r < 4; ++r) dm = (c == r) ? d[r] : dm;
                float a = adj[row];
                float attn = 0.f;
                if (a != 0.f) {
                    float score = (s_b + a * dm) * inv;
                    float e = __expf(2.f * score);        // fast tanh
                    attn = 10.f * ((e - 1.f) / (e + 1.f));
                    if (score > bscore) { bscore = score; bidx = row; }
                }
                zloc += __expf(attn);
            }
        }
    }
    // wave-wide reduce
#pragma unroll
    for (int m = 32; m >= 1; m >>= 1) zloc += __shfl_xor(zloc, m);
    unsigned long long pk = 0ull;
    if (bidx >= 0)
        pk = ((unsigned long long)fkey(bscore) << 32) |
             (unsigned long long)(0xFFFFFFFFu - (unsigned int)bidx);
#pragma unroll
    for (int m = 32; m >= 1; m >>= 1) {
        unsigned long long o = __shfl_xor(pk, m);
        if (o > pk) pk = o;
    }
    if (lane == 0) { zs[w] = zloc; bs[w] = pk; }
    __syncthreads();
    if (t == 0) {
        float z = zs[0] + zs[1] + zs[2] + zs[3];
        unsigned long long p2 = bs[0];
#pragma unroll
        for (int i = 1; i < 4; ++i) if (bs[i] > p2) p2 = bs[i];
        ws->Z_part[blockIdx.x] = z;            // plain stores, own slot
        ws->best_part[blockIdx.x] = p2;
    }
}

// ---------------- reduce: 1 block, 1024 threads -------------------------------
__global__ __launch_bounds__(1024)
void reduce_kernel(const Ws* __restrict__ ws, float* __restrict__ outp) {
    __shared__ float zs[16];
    __shared__ unsigned long long bs[16];
    int t = threadIdx.x;
    int lane = t & 63;
    float z = ws->Z_part[t] + ws->Z_part[t + 1024];
    unsigned long long pk = ws->best_part[t];
    unsigned long long o2 = ws->best_part[t + 1024];
    if (o2 > pk) pk = o2;
#pragma unroll
    for (int m = 32; m >= 1; m >>= 1) {
        z += __shfl_xor(z, m);
        unsigned long long o = __shfl_xor(pk, m);
        if (o > pk) pk = o;
    }
    if (lane == 0) { zs[t >> 6] = z; bs[t >> 6] = pk; }
    __syncthreads();
    if (t == 0) {
        float Z = 0.f;
        unsigned long long b = 0ull;
#pragma unroll
        for (int i = 0; i < 16; ++i) { Z += zs[i]; if (bs[i] > b) b = bs[i]; }
        unsigned int idx = 0xFFFFFFFFu - (unsigned int)(b & 0xFFFFFFFFu);
        float score = inv_fkey((unsigned int)(b >> 32));
        float p = __expf(10.f * tanhf(score)) / Z;
        if (b == 0ull) { idx = 0; p = 0.f; }
        outp[0] = (float)idx;
        outp[1] = p;
    }
}

extern "C" void kernel_launch(void* const* d_in, const int* in_sizes, int n_in,
                              void* d_out, int out_size, void* d_ws, size_t ws_size,
                              hipStream_t stream) {
    const float* outp = (const float*)d_in[0];
    const float* adj  = (const float*)d_in[1];
    const float* W1   = (const float*)d_in[2];
    const float* b1   = (const float*)d_in[3];
    const float* W2   = (const float*)d_in[4];
    const float* b2   = (const float*)d_in[5];
    const int*   prev = (const int*)d_in[6];
    int n = in_sizes[1];                       // N = 200000
    Ws* ws = (Ws*)d_ws;

    int ntiles = (n + 31) / 32;                // 6250

    prep_kernel<<<1, 1024, 0, stream>>>(outp, W1, b1, W2, b2, prev, ws);
    score_kernel<<<GRID, 256, 0, stream>>>((const float4*)outp, adj, ws, n, ntiles);
    reduce_kernel<<<1, 1024, 0, stream>>>(ws, (float*)d_out);
}

// Round 4
// 168.980 us; speedup vs baseline: 1.3244x; 1.0957x over previous
//
#include <hip/hip_runtime.h>
#include <math.h>

#define H 128
#define HID 512
#define GRID 2048          // score blocks == partial slots
#define PREP_B 16          // prep blocks == u partial slots

struct Ws {
    float sb_part[PREP_B];
    float u_part[PREP_B][H];
    unsigned long long best_part[GRID];   // offset 64+8192=8256, 8-aligned
    float Z_part[GRID];
};

__device__ __forceinline__ unsigned int fkey(float f) {
    unsigned int u = __float_as_uint(f);
    return (u & 0x80000000u) ? ~u : (u | 0x80000000u);
}
__device__ __forceinline__ float inv_fkey(unsigned int k) {
    return __uint_as_float((k & 0x80000000u) ? (k ^ 0x80000000u) : ~k);
}

// ---------------- prep: 16 independent blocks, no cross-block deps ------------
// Block b owns k-chunk [32b, 32b+32):
//   phi1[k] = W1[k,:].v_i + b1[k]   (half-wave per 4 rows, butterfly reduce)
//   u_part[b][h] = sum_k phi1[k] * W2[k][h]
//   sb_part[b]   = sum_k phi1[k] * b2[k]
__global__ __launch_bounds__(256)
void prep_kernel(const float* __restrict__ outp, const float* __restrict__ W1,
                 const float* __restrict__ b1, const float* __restrict__ W2,
                 const float* __restrict__ b2, const int* __restrict__ prev,
                 Ws* __restrict__ ws) {
    __shared__ float phi1_s[32];
    __shared__ float sb_s[8];
    __shared__ float u_s[2][H];
    int t = threadIdx.x;
    int lane = t & 63;
    int c = lane & 31;
    int g = t >> 5;            // half-wave id 0..7, each owns 4 rows
    int kbase = blockIdx.x * 32;
    const float4* vi = (const float4*)(outp + (size_t)prev[0] * H);
    float4 v = vi[c];
    float sb = 0.f;
#pragma unroll
    for (int r = 0; r < 4; ++r) {
        int kl = g * 4 + r;                  // 0..31
        int k = kbase + kl;
        float4 w = ((const float4*)(W1 + (size_t)k * H))[c];
        float d = w.x * v.x + w.y * v.y + w.z * v.z + w.w * v.w;
        d += __shfl_xor(d, 16);
        d += __shfl_xor(d, 8);
        d += __shfl_xor(d, 4);
        d += __shfl_xor(d, 2);
        d += __shfl_xor(d, 1);
        if (c == 0) {
            float phi = d + b1[k];
            phi1_s[kl] = phi;
            sb += phi * b2[k];
        }
    }
    if (c == 0) sb_s[g] = sb;
    __syncthreads();
    // u partial: h = t&127, k-halves by g2
    int h = t & 127;
    int g2 = t >> 7;           // 0..1
    float up = 0.f;
#pragma unroll
    for (int kk = 0; kk < 16; ++kk) {
        int kl = g2 * 16 + kk;
        up += phi1_s[kl] * W2[(size_t)(kbase + kl) * H + h];
    }
    u_s[g2][h] = up;
    __syncthreads();
    if (t < H) ws->u_part[blockIdx.x][t] = u_s[0][t] + u_s[1][t];
    if (t == 0) {
        float s = 0.f;
#pragma unroll
        for (int i = 0; i < 8; ++i) s += sb_s[i];
        ws->sb_part[blockIdx.x] = s;
    }
}

// ---------------- main streaming pass: NO global atomics ----------------------
// Tile = 32 rows/block-iter. Wave w owns rows tile*32 + w*8 .. +7.
// Half-wave handles 4 rows (row = base + 2r), 4 float4 loads in flight,
// independent butterfly chains, tail fanned over lanes 0..3.
__global__ __launch_bounds__(256)
void score_kernel(const float4* __restrict__ xv, const float* __restrict__ adj,
                  Ws* __restrict__ ws, int n, int ntiles) {
    __shared__ float zs[4];
    __shared__ unsigned long long bs[4];
    const float inv = 0.04419417382415922f;   // 1/sqrt(512)
    int t = threadIdx.x;
    int lane = t & 63;
    int c = lane & 31;
    int hv = lane >> 5;
    int w = t >> 6;
    // fold the 16 u/sb partials (8 KB, L2/L3-hot)
    float4 uv = make_float4(0.f, 0.f, 0.f, 0.f);
    float s_b = 0.f;
#pragma unroll
    for (int b = 0; b < PREP_B; ++b) {
        float4 p = ((const float4*)ws->u_part[b])[c];
        uv.x += p.x; uv.y += p.y; uv.z += p.z; uv.w += p.w;
        s_b += ws->sb_part[b];
    }
    float zloc = 0.f;
    float bscore = -3.4e38f;
    int bidx = -1;
    for (int tile = blockIdx.x; tile < ntiles; tile += GRID) {
        int base = tile * 32 + w * 8 + hv;
        float4 x[4];
#pragma unroll
        for (int r = 0; r < 4; ++r) {
            int row = base + 2 * r;
            if (row >= n) row = n - 1;            // clamp (value unused OOB)
            x[r] = xv[(size_t)row * 32 + c];
        }
        float d[4];
#pragma unroll
        for (int r = 0; r < 4; ++r) {
            float dd = x[r].x * uv.x + x[r].y * uv.y + x[r].z * uv.z + x[r].w * uv.w;
            dd += __shfl_xor(dd, 16);
            dd += __shfl_xor(dd, 8);
            dd += __shfl_xor(dd, 4);
            dd += __shfl_xor(dd, 2);
            dd += __shfl_xor(dd, 1);
            d[r] = dd;
        }
        if (c < 4) {
            int row = base + 2 * c;
            if (row < n) {
                float dm = d[0];
#pragma unroll
                for (int r = 1; r < 4; ++r) dm = (c == r) ? d[r] : dm;
                float a = adj[row];
                float attn = 0.f;
                if (a != 0.f) {
                    float score = (s_b + a * dm) * inv;
                    float e = __expf(2.f * score);        // fast tanh
                    attn = 10.f * ((e - 1.f) / (e + 1.f));
                    if (score > bscore) { bscore = score; bidx = row; }
                }
                zloc += __expf(attn);
            }
        }
    }
    // wave-wide reduce
#pragma unroll
    for (int m = 32; m >= 1; m >>= 1) zloc += __shfl_xor(zloc, m);
    unsigned long long pk = 0ull;
    if (bidx >= 0)
        pk = ((unsigned long long)fkey(bscore) << 32) |
             (unsigned long long)(0xFFFFFFFFu - (unsigned int)bidx);
#pragma unroll
    for (int m = 32; m >= 1; m >>= 1) {
        unsigned long long o = __shfl_xor(pk, m);
        if (o > pk) pk = o;
    }
    if (lane == 0) { zs[w] = zloc; bs[w] = pk; }
    __syncthreads();
    if (t == 0) {
        float z = zs[0] + zs[1] + zs[2] + zs[3];
        unsigned long long p2 = bs[0];
#pragma unroll
        for (int i = 1; i < 4; ++i) if (bs[i] > p2) p2 = bs[i];
        ws->Z_part[blockIdx.x] = z;            // plain stores, own slot
        ws->best_part[blockIdx.x] = p2;
    }
}

// ---------------- reduce: 1 block, 1024 threads -------------------------------
__global__ __launch_bounds__(1024)
void reduce_kernel(const Ws* __restrict__ ws, float* __restrict__ outp) {
    __shared__ float zs[16];
    __shared__ unsigned long long bs[16];
    int t = threadIdx.x;
    int lane = t & 63;
    float z = ws->Z_part[t] + ws->Z_part[t + 1024];
    unsigned long long pk = ws->best_part[t];
    unsigned long long o2 = ws->best_part[t + 1024];
    if (o2 > pk) pk = o2;
#pragma unroll
    for (int m = 32; m >= 1; m >>= 1) {
        z += __shfl_xor(z, m);
        unsigned long long o = __shfl_xor(pk, m);
        if (o > pk) pk = o;
    }
    if (lane == 0) { zs[t >> 6] = z; bs[t >> 6] = pk; }
    __syncthreads();
    if (t == 0) {
        float Z = 0.f;
        unsigned long long b = 0ull;
#pragma unroll
        for (int i = 0; i < 16; ++i) { Z += zs[i]; if (bs[i] > b) b = bs[i]; }
        unsigned int idx = 0xFFFFFFFFu - (unsigned int)(b & 0xFFFFFFFFu);
        float score = inv_fkey((unsigned int)(b >> 32));
        float p = __expf(10.f * tanhf(score)) / Z;
        if (b == 0ull) { idx = 0; p = 0.f; }
        outp[0] = (float)idx;
        outp[1] = p;
    }
}

extern "C" void kernel_launch(void* const* d_in, const int* in_sizes, int n_in,
                              void* d_out, int out_size, void* d_ws, size_t ws_size,
                              hipStream_t stream) {
    const float* outp = (const float*)d_in[0];
    const float* adj  = (const float*)d_in[1];
    const float* W1   = (const float*)d_in[2];
    const float* b1   = (const float*)d_in[3];
    const float* W2   = (const float*)d_in[4];
    const float* b2   = (const float*)d_in[5];
    const int*   prev = (const int*)d_in[6];
    int n = in_sizes[1];                       // N = 200000
    Ws* ws = (Ws*)d_ws;

    int ntiles = (n + 31) / 32;                // 6250

    prep_kernel<<<PREP_B, 256, 0, stream>>>(outp, W1, b1, W2, b2, prev, ws);
    score_kernel<<<GRID, 256, 0, stream>>>((const float4*)outp, adj, ws, n, ntiles);
    reduce_kernel<<<1, 1024, 0, stream>>>(ws, (float*)d_out);
}

// Round 5
// 167.597 us; speedup vs baseline: 1.3353x; 1.0082x over previous
//
#include <hip/hip_runtime.h>
#include <math.h>

#define H 128
#define HID 512
#define GRID 2048          // score blocks == partial slots
#define PREP_B 16          // prep blocks == u partial slots

struct Ws {
    float sb_part[PREP_B];
    float u_part[PREP_B][H];
    unsigned long long best_part[GRID];   // 8-aligned
    float Z_part[GRID];
};

__device__ __forceinline__ unsigned int fkey(float f) {
    unsigned int u = __float_as_uint(f);
    return (u & 0x80000000u) ? ~u : (u | 0x80000000u);
}
__device__ __forceinline__ float inv_fkey(unsigned int k) {
    return __uint_as_float((k & 0x80000000u) ? (k ^ 0x80000000u) : ~k);
}

// ---------------- prep: 16 independent blocks, no cross-block deps ------------
__global__ __launch_bounds__(256)
void prep_kernel(const float* __restrict__ outp, const float* __restrict__ W1,
                 const float* __restrict__ b1, const float* __restrict__ W2,
                 const float* __restrict__ b2, const int* __restrict__ prev,
                 Ws* __restrict__ ws) {
    __shared__ float phi1_s[32];
    __shared__ float sb_s[8];
    __shared__ float u_s[2][H];
    int t = threadIdx.x;
    int lane = t & 63;
    int c = lane & 31;
    int g = t >> 5;            // half-wave id 0..7, each owns 4 rows
    int kbase = blockIdx.x * 32;
    const float4* vi = (const float4*)(outp + (size_t)prev[0] * H);
    float4 v = vi[c];
    float sb = 0.f;
#pragma unroll
    for (int r = 0; r < 4; ++r) {
        int kl = g * 4 + r;
        int k = kbase + kl;
        float4 w = ((const float4*)(W1 + (size_t)k * H))[c];
        float d = w.x * v.x + w.y * v.y + w.z * v.z + w.w * v.w;
        d += __shfl_xor(d, 16);
        d += __shfl_xor(d, 8);
        d += __shfl_xor(d, 4);
        d += __shfl_xor(d, 2);
        d += __shfl_xor(d, 1);
        if (c == 0) {
            float phi = d + b1[k];
            phi1_s[kl] = phi;
            sb += phi * b2[k];
        }
    }
    if (c == 0) sb_s[g] = sb;
    __syncthreads();
    int h = t & 127;
    int g2 = t >> 7;           // 0..1
    float up = 0.f;
#pragma unroll
    for (int kk = 0; kk < 16; ++kk) {
        int kl = g2 * 16 + kk;
        up += phi1_s[kl] * W2[(size_t)(kbase + kl) * H + h];
    }
    u_s[g2][h] = up;
    __syncthreads();
    if (t < H) ws->u_part[blockIdx.x][t] = u_s[0][t] + u_s[1][t];
    if (t == 0) {
        float s = 0.f;
#pragma unroll
        for (int i = 0; i < 8; ++i) s += sb_s[i];
        ws->sb_part[blockIdx.x] = s;
    }
}

// ---------------- main streaming pass: adj-gated, NO global atomics -----------
// Wave w owns rows [tile*32 + w*8, +8). Lanes 0..7 prefetch the 8 adj values;
// each half-wave then runs 4 dot-chains, each predicated on its (half-wave
// uniform) adj value: adj==0 rows issue NO x-load and NO shuffle chain —
// they only contribute exp(0)=1 to Z. ~50% of adj is zero -> ~half the bytes.
__global__ __launch_bounds__(256)
void score_kernel(const float4* __restrict__ xv, const float* __restrict__ adj,
                  Ws* __restrict__ ws, int n, int ntiles) {
    __shared__ float zs[4];
    __shared__ unsigned long long bs[4];
    const float inv = 0.04419417382415922f;   // 1/sqrt(512)
    int t = threadIdx.x;
    int lane = t & 63;
    int c = lane & 31;
    int hv = lane >> 5;
    int w = t >> 6;
    // fold the 16 u/sb partials (8 KB, L2/L3-hot)
    float4 uv = make_float4(0.f, 0.f, 0.f, 0.f);
    float s_b = 0.f;
#pragma unroll
    for (int b = 0; b < PREP_B; ++b) {
        float4 p = ((const float4*)ws->u_part[b])[c];
        uv.x += p.x; uv.y += p.y; uv.z += p.z; uv.w += p.w;
        s_b += ws->sb_part[b];
    }
    float zloc = 0.f;
    float bscore = -3.4e38f;
    int bidx = -1;
    for (int tile = blockIdx.x; tile < ntiles; tile += GRID) {
        int rowbase = tile * 32 + w * 8;
        float av = 0.f;
        if (lane < 8 && rowbase + lane < n) av = adj[rowbase + lane];
        float a4[4];
        float d[4];
        // predicated loads + partial dots (loads grouped, no waitcnt until use)
#pragma unroll
        for (int r = 0; r < 4; ++r) {
            a4[r] = __shfl(av, hv + 2 * r);
            float dd = 0.f;
            if (a4[r] != 0.f) {
                int row = rowbase + hv + 2 * r;
                float4 x = xv[(size_t)row * 32 + c];
                dd = x.x * uv.x + x.y * uv.y + x.z * uv.z + x.w * uv.w;
            }
            d[r] = dd;
        }
        // butterfly reductions, only for live rows (xor<=16 stays in half-wave)
#pragma unroll
        for (int r = 0; r < 4; ++r) {
            if (a4[r] != 0.f) {
                float dd = d[r];
                dd += __shfl_xor(dd, 16);
                dd += __shfl_xor(dd, 8);
                dd += __shfl_xor(dd, 4);
                dd += __shfl_xor(dd, 2);
                dd += __shfl_xor(dd, 1);
                d[r] = dd;
            }
        }
        // tail: lanes c<4 own row r=c
        if (c < 4) {
            int row = rowbase + hv + 2 * c;
            if (row < n) {
                float a = a4[0];
                float dm = d[0];
#pragma unroll
                for (int r = 1; r < 4; ++r) {
                    a  = (c == r) ? a4[r] : a;
                    dm = (c == r) ? d[r] : dm;
                }
                if (a != 0.f) {
                    float score = (s_b + a * dm) * inv;
                    float e = __expf(2.f * score);        // fast tanh
                    float attn = 10.f * ((e - 1.f) / (e + 1.f));
                    zloc += __expf(attn);
                    if (score > bscore) { bscore = score; bidx = row; }
                } else {
                    zloc += 1.0f;                          // exp(0)
                }
            }
        }
    }
    // wave-wide reduce
#pragma unroll
    for (int m = 32; m >= 1; m >>= 1) zloc += __shfl_xor(zloc, m);
    unsigned long long pk = 0ull;
    if (bidx >= 0)
        pk = ((unsigned long long)fkey(bscore) << 32) |
             (unsigned long long)(0xFFFFFFFFu - (unsigned int)bidx);
#pragma unroll
    for (int m = 32; m >= 1; m >>= 1) {
        unsigned long long o = __shfl_xor(pk, m);
        if (o > pk) pk = o;
    }
    if (lane == 0) { zs[w] = zloc; bs[w] = pk; }
    __syncthreads();
    if (t == 0) {
        float z = zs[0] + zs[1] + zs[2] + zs[3];
        unsigned long long p2 = bs[0];
#pragma unroll
        for (int i = 1; i < 4; ++i) if (bs[i] > p2) p2 = bs[i];
        ws->Z_part[blockIdx.x] = z;            // plain stores, own slot
        ws->best_part[blockIdx.x] = p2;
    }
}

// ---------------- reduce: 1 block, 1024 threads -------------------------------
__global__ __launch_bounds__(1024)
void reduce_kernel(const Ws* __restrict__ ws, float* __restrict__ outp) {
    __shared__ float zs[16];
    __shared__ unsigned long long bs[16];
    int t = threadIdx.x;
    int lane = t & 63;
    float z = ws->Z_part[t] + ws->Z_part[t + 1024];
    unsigned long long pk = ws->best_part[t];
    unsigned long long o2 = ws->best_part[t + 1024];
    if (o2 > pk) pk = o2;
#pragma unroll
    for (int m = 32; m >= 1; m >>= 1) {
        z += __shfl_xor(z, m);
        unsigned long long o = __shfl_xor(pk, m);
        if (o > pk) pk = o;
    }
    if (lane == 0) { zs[t >> 6] = z; bs[t >> 6] = pk; }
    __syncthreads();
    if (t == 0) {
        float Z = 0.f;
        unsigned long long b = 0ull;
#pragma unroll
        for (int i = 0; i < 16; ++i) { Z += zs[i]; if (bs[i] > b) b = bs[i]; }
        unsigned int idx = 0xFFFFFFFFu - (unsigned int)(b & 0xFFFFFFFFu);
        float score = inv_fkey((unsigned int)(b >> 32));
        float p = __expf(10.f * tanhf(score)) / Z;
        if (b == 0ull) { idx = 0; p = 0.f; }
        outp[0] = (float)idx;
        outp[1] = p;
    }
}

extern "C" void kernel_launch(void* const* d_in, const int* in_sizes, int n_in,
                              void* d_out, int out_size, void* d_ws, size_t ws_size,
                              hipStream_t stream) {
    const float* outp = (const float*)d_in[0];
    const float* adj  = (const float*)d_in[1];
    const float* W1   = (const float*)d_in[2];
    const float* b1   = (const float*)d_in[3];
    const float* W2   = (const float*)d_in[4];
    const float* b2   = (const float*)d_in[5];
    const int*   prev = (const int*)d_in[6];
    int n = in_sizes[1];                       // N = 200000
    Ws* ws = (Ws*)d_ws;

    int ntiles = (n + 31) / 32;                // 6250

    prep_kernel<<<PREP_B, 256, 0, stream>>>(outp, W1, b1, W2, b2, prev, ws);
    score_kernel<<<GRID, 256, 0, stream>>>((const float4*)outp, adj, ws, n, ntiles);
    reduce_kernel<<<1, 1024, 0, stream>>>(ws, (float*)d_out);
}